// Round 1
// baseline (186.889 us; speedup 1.0000x reference)
//
#include <hip/hip_runtime.h>

#define B_ 4
#define N_ 256
#define M_ 256
#define O_ 16
#define P_ 16
#define CIN_ 32
#define COUT_ 32
#define KD_ 16
#define NC_ 32

// ---------- Kernel 1: fkT[oc][pd] = sum_k fb[p,o,k] * Wf[d*32+c, k] / 1024
__global__ __launch_bounds__(256) void fk_kernel(const float* __restrict__ fb,
                                                 const float* __restrict__ Wf,
                                                 float* __restrict__ fkT) {
  int gid = blockIdx.x * 256 + threadIdx.x;
#pragma unroll
  for (int i = 0; i < 4; ++i) {
    int idx = gid + i * 65536;          // 262144 outputs total
    int pd = idx & 511;
    int oc = idx >> 9;
    int o = oc >> 5, c = oc & 31;
    int p = pd >> 5, d = pd & 31;
    const float4* fb4 = (const float4*)(fb + (p * 16 + o) * 16);
    const float4* wf4 = (const float4*)(Wf + (d * 32 + c) * 16);
    float s = 0.f;
#pragma unroll
    for (int q = 0; q < 4; ++q) {
      float4 a = fb4[q], w = wf4[q];
      s += a.x * w.x + a.y * w.y + a.z * w.z + a.w * w.w;
    }
    fkT[idx] = s * (1.0f / 1024.0f);
  }
}

// ---------- async global->LDS helper (16B per lane)
__device__ __forceinline__ void gload_lds16(float* l, const float* g) {
#if defined(__has_builtin) && __has_builtin(__builtin_amdgcn_global_load_lds)
  __builtin_amdgcn_global_load_lds((const __attribute__((address_space(1))) void*)g,
                                   (__attribute__((address_space(3))) void*)l, 16, 0, 0);
#else
  *(float4*)l = *(const float4*)g;
#endif
}

// ---------- Kernel 2: per (b,m): x1[o,c] = sum_n x[b,n,o,c] * (sum_k KB[b,m,n,o,k]*Wk[c,k])
__global__ __launch_bounds__(256) void main_kernel(const float* __restrict__ x,
                                                   const float* __restrict__ kb,
                                                   const float* __restrict__ Wk,
                                                   float* __restrict__ x1out) {
  __shared__ float lds[NC_ * 256];  // 32 KB: NC_ rows of [o=16][k=16]
  const int tid = threadIdx.x;
  const int bm = blockIdx.x;        // b*256 + m
  const int b = bm >> 8;
  const int c = tid & 31;
  const int o0 = tid >> 5;          // 0..7
  const int o1 = o0 + 8;

  float wkr[16];
  {
    const float4* w4 = (const float4*)(Wk + c * 16);
#pragma unroll
    for (int q = 0; q < 4; ++q) {
      float4 v = w4[q];
      wkr[q * 4 + 0] = v.x; wkr[q * 4 + 1] = v.y;
      wkr[q * 4 + 2] = v.z; wkr[q * 4 + 3] = v.w;
    }
  }

  const float* kbb = kb + (size_t)bm * 65536;       // KB[b,m,:,:,:]
  const float* xb  = x + b * (N_ * O_ * CIN_);      // x[b,:,:,:]
  float acc0 = 0.f, acc1 = 0.f;

  for (int ch = 0; ch < N_ / NC_; ++ch) {
    __syncthreads();  // all waves done reading previous chunk
    {
      const float* src = kbb + ch * (NC_ * 256) + tid * 4;
      float* dst = lds + tid * 4;
#pragma unroll
      for (int i = 0; i < 8; ++i)
        gload_lds16(dst + i * 1024, src + i * 1024);
    }
    __syncthreads();  // staged data visible (vmcnt drained by barrier)

    const float* xrow = xb + (ch * NC_) * (O_ * CIN_);
#pragma unroll 4
    for (int n = 0; n < NC_; ++n) {
      const float4* k0p = (const float4*)(lds + n * 256 + o0 * 16);
      const float4* k1p = (const float4*)(lds + n * 256 + o1 * 16);
      float s0 = 0.f, s1 = 0.f;
#pragma unroll
      for (int q = 0; q < 4; ++q) {
        float4 a = k0p[q];
        s0 += a.x * wkr[q * 4] + a.y * wkr[q * 4 + 1] + a.z * wkr[q * 4 + 2] + a.w * wkr[q * 4 + 3];
        float4 bq = k1p[q];
        s1 += bq.x * wkr[q * 4] + bq.y * wkr[q * 4 + 1] + bq.z * wkr[q * 4 + 2] + bq.w * wkr[q * 4 + 3];
      }
      float xv0 = xrow[n * 512 + o0 * 32 + c];
      float xv1 = xrow[n * 512 + o1 * 32 + c];
      acc0 = fmaf(s0, xv0, acc0);
      acc1 = fmaf(s1, xv1, acc1);
    }
  }

  x1out[bm * 512 + o0 * 32 + c] = acc0;
  x1out[bm * 512 + o1 * 32 + c] = acc1;
}

// ---------- Kernel 3: out[bm, pd] = sum_oc x1[bm, oc] * fkT[oc, pd] + bias[pd&31]
__global__ __launch_bounds__(256) void fiber_kernel(const float* __restrict__ x1,
                                                    const float* __restrict__ fkT,
                                                    const float* __restrict__ bias,
                                                    float* __restrict__ out) {
  __shared__ float At[32][68];  // A-tile transposed [k][row], padded: stride 272B (16B aligned)
  __shared__ float Bt[32][64];  // B-tile [k][col]
  const int tid = threadIdx.x;
  const int bx = blockIdx.x & 7;   // col tile: 512/64
  const int by = blockIdx.x >> 3;  // row tile: 1024/64
  const int tr = tid >> 4, tc = tid & 15;
  const int row0 = by * 64, col0 = bx * 64;
  float acc[4][4] = {};

  for (int kc = 0; kc < 512; kc += 32) {
    __syncthreads();
    {
      int r8 = tid >> 3, kq = tid & 7;
#pragma unroll
      for (int ii = 0; ii < 2; ++ii) {
        int r = r8 + ii * 32;
        float4 a = *(const float4*)(x1 + (row0 + r) * 512 + kc + kq * 4);
        At[kq * 4 + 0][r] = a.x; At[kq * 4 + 1][r] = a.y;
        At[kq * 4 + 2][r] = a.z; At[kq * 4 + 3][r] = a.w;
      }
#pragma unroll
      for (int ii = 0; ii < 2; ++ii) {
        int idx = tid + ii * 256;
        int k = idx >> 4, c4 = idx & 15;
        *(float4*)&Bt[k][c4 * 4] = *(const float4*)(fkT + (kc + k) * 512 + col0 + c4 * 4);
      }
    }
    __syncthreads();
#pragma unroll 8
    for (int k = 0; k < 32; ++k) {
      float4 av = *(const float4*)&At[k][tr * 4];
      float4 bv = *(const float4*)&Bt[k][tc * 4];
      float ar[4] = {av.x, av.y, av.z, av.w};
      float br[4] = {bv.x, bv.y, bv.z, bv.w};
#pragma unroll
      for (int i = 0; i < 4; ++i)
#pragma unroll
        for (int j = 0; j < 4; ++j)
          acc[i][j] = fmaf(ar[i], br[j], acc[i][j]);
    }
  }

  float4 bias4 = *(const float4*)(bias + ((tc * 4) & 31));
  float bb[4] = {bias4.x, bias4.y, bias4.z, bias4.w};
#pragma unroll
  for (int i = 0; i < 4; ++i) {
    float4 o4;
    o4.x = acc[i][0] + bb[0]; o4.y = acc[i][1] + bb[1];
    o4.z = acc[i][2] + bb[2]; o4.w = acc[i][3] + bb[3];
    *(float4*)(out + (row0 + tr * 4 + i) * 512 + col0 + tc * 4) = o4;
  }
}

extern "C" void kernel_launch(void* const* d_in, const int* in_sizes, int n_in,
                              void* d_out, int out_size, void* d_ws, size_t ws_size,
                              hipStream_t stream) {
  const float* x    = (const float*)d_in[0];  // [4,256,16,32]
  const float* kbas = (const float*)d_in[1];  // [4,256,256,16,16]
  const float* fb   = (const float*)d_in[2];  // [16,16,16]
  const float* Wk   = (const float*)d_in[3];  // [32,16]
  const float* Wf   = (const float*)d_in[4];  // [1024,16]
  const float* bias = (const float*)d_in[5];  // [32]
  float* out = (float*)d_out;                 // [4,256,16,32] f32

  float* fkT = (float*)d_ws;        // 262144 floats (1 MB)
  float* x1  = fkT + 262144;        // 524288 floats (2 MB)

  fk_kernel<<<256, 256, 0, stream>>>(fb, Wf, fkT);
  main_kernel<<<1024, 256, 0, stream>>>(x, kbas, Wk, x1);
  fiber_kernel<<<128, 256, 0, stream>>>(x1, fkT, bias, out);
}

// Round 2
// 141.493 us; speedup vs baseline: 1.3208x; 1.3208x over previous
//
#include <hip/hip_runtime.h>
#include <hip/hip_bf16.h>

#define B_ 4
#define N_ 256
#define M_ 256
#define O_ 16
#define P_ 16
#define CIN_ 32
#define COUT_ 32
#define KD_ 16
#define NC_ 32

typedef __attribute__((ext_vector_type(8))) short short8_t;   // 8 bf16 (4 VGPRs)
typedef __attribute__((ext_vector_type(4))) short short4_t;   // 4 bf16
typedef __attribute__((ext_vector_type(4))) float floatx4;

__device__ __forceinline__ short bf16_of(float f) {
  __hip_bfloat16 h = __float2bfloat16(f);
  return __builtin_bit_cast(short, h);
}

// ---------- async global->LDS helper (16B per lane)
__device__ __forceinline__ void gload_lds16(void* l, const void* g) {
#if defined(__has_builtin) && __has_builtin(__builtin_amdgcn_global_load_lds)
  __builtin_amdgcn_global_load_lds((const __attribute__((address_space(1))) void*)g,
                                   (__attribute__((address_space(3))) void*)l, 16, 0, 0);
#else
  *(float4*)l = *(const float4*)g;
#endif
}

// ---------- Kernel 1: fkT[oc][pd] = sum_k fb[p,o,k] * Wf[d*32+c, k] / 1024
__global__ __launch_bounds__(256) void fk_kernel(const float* __restrict__ fb,
                                                 const float* __restrict__ Wf,
                                                 float* __restrict__ fkT) {
  int gid = blockIdx.x * 256 + threadIdx.x;
#pragma unroll
  for (int i = 0; i < 4; ++i) {
    int idx = gid + i * 65536;
    int pd = idx & 511;
    int oc = idx >> 9;
    int o = oc >> 5, c = oc & 31;
    int p = pd >> 5, d = pd & 31;
    const float4* fb4 = (const float4*)(fb + (p * 16 + o) * 16);
    const float4* wf4 = (const float4*)(Wf + (d * 32 + c) * 16);
    float s = 0.f;
#pragma unroll
    for (int q = 0; q < 4; ++q) {
      float4 a = fb4[q], w = wf4[q];
      s += a.x * w.x + a.y * w.y + a.z * w.z + a.w * w.w;
    }
    fkT[idx] = s * (1.0f / 1024.0f);
  }
}

// ---------- Kernel 2: B2s[(b*16+o)][c][K] bf16, pre-swizzled: elem K stored at K ^ ((c&7)<<3)
// B2[bo][c][n*16+k] = x[b,n,o,c] * Wk[c,k]
__global__ __launch_bounds__(256) void b2_kernel(const float* __restrict__ x,
                                                 const float* __restrict__ Wk,
                                                 short* __restrict__ b2s) {
  int g = blockIdx.x * 256 + threadIdx.x;  // [0, 1048576)
  int run = g & 511;                       // 8-elem K-run
  int c = (g >> 9) & 31;
  int bo = g >> 14;
  int b = bo >> 4, o = bo & 15;
  int n = run >> 1, k0 = (run & 1) * 8;
  float xv = x[((b * 256 + n) * 16 + o) * 32 + c];
  const float4* w4 = (const float4*)(Wk + c * 16 + k0);
  float4 w0 = w4[0], w1 = w4[1];
  short8_t v;
  v[0] = bf16_of(xv * w0.x); v[1] = bf16_of(xv * w0.y);
  v[2] = bf16_of(xv * w0.z); v[3] = bf16_of(xv * w0.w);
  v[4] = bf16_of(xv * w1.x); v[5] = bf16_of(xv * w1.y);
  v[6] = bf16_of(xv * w1.z); v[7] = bf16_of(xv * w1.w);
  int dst = (bo * 32 + c) * 4096 + ((run * 8) ^ ((c & 7) << 3));
  *(short8_t*)(b2s + dst) = v;
}

// ---------- Kernel 3: MFMA GEMM per (b,o,mtile=32): C[32m x 32c] = sum_K A[m,K] B2[K,c]
// A = KB[b, mt*32+m, n, o, k] (K = n*16+k), staged f32->bf16 into LDS (XOR-swizzled).
// B2 staged via global_load_lds (global is pre-swizzled -> linear load, swizzled read).
__global__ __launch_bounds__(256) void gemm_kernel(const float* __restrict__ kb,
                                                   const short* __restrict__ b2s,
                                                   float* __restrict__ x1) {
  __shared__ __align__(16) short As[32 * 256];      // 16 KB, single buffer (chunk KC=256)
  __shared__ __align__(16) short Bs[2][32 * 256];   // 2 x 16 KB double buffer
  const int tid = threadIdx.x;
  const int bid = blockIdx.x;          // bid = mt*64 + bo -> same-bo blocks share XCD (mod 8)
  const int mt = bid >> 6;             // [0,8)
  const int bo = bid & 63;
  const int b = bo >> 4, o = bo & 15;
  const int lane = tid & 63, wave = tid >> 6;
  const int mq = (wave >> 1) * 16;     // wave's m-offset in [0,32)
  const int chalf = (wave & 1) * 16;   // wave's c-offset in [0,32)

  // --- A staging addressing: 512 segs (32m x 16n) of 64B; 4 lanes/seg; 8 iters
  const int q = tid & 3;
  const int m0 = (tid >> 2) >> 4;      // [0,4)
  const int n0 = (tid >> 2) & 15;
  const float* gA = kb + (size_t)(b * 256 + mt * 32 + m0) * 65536 + n0 * 256 + o * 16 + q * 4;
  int awr[8];
#pragma unroll
  for (int i = 0; i < 8; ++i) {
    int mi = m0 + i * 4;
    awr[i] = mi * 512 + ((n0 * 32 + q * 8) ^ ((mi & 7) << 4));  // LDS byte, chunk-invariant
  }
  // --- B staging addressing: 16 KB/chunk, 4 iters of 256x16B
  const int bc0 = tid >> 5;            // +it*8 rows
  const int bx = (tid & 31) * 8;       // elems
  const short* gB = b2s + (size_t)(bo * 32 + bc0) * 4096 + bx;

  floatx4 acc = {0.f, 0.f, 0.f, 0.f};
  float4 aregs[8];

#define LOAD_A(nc_)                                                              \
  {                                                                              \
    _Pragma("unroll") for (int i = 0; i < 8; ++i)                                \
        aregs[i] = *(const float4*)(gA + (size_t)(nc_)*4096 + (size_t)i * 4 * 65536); \
  }
#define STAGE_B(buf_, nc_)                                                       \
  {                                                                              \
    _Pragma("unroll") for (int it = 0; it < 4; ++it)                             \
        gload_lds16(&Bs[buf_][(size_t)tid * 8 + (size_t)it * 2048],              \
                    gB + (size_t)it * 8 * 4096 + (nc_)*256);                     \
  }
#define WRITE_A()                                                                \
  {                                                                              \
    _Pragma("unroll") for (int i = 0; i < 8; ++i) {                              \
      short4_t v;                                                                \
      v[0] = bf16_of(aregs[i].x); v[1] = bf16_of(aregs[i].y);                    \
      v[2] = bf16_of(aregs[i].z); v[3] = bf16_of(aregs[i].w);                    \
      *(short4_t*)((char*)As + awr[i] + 0) = v;                                  \
    }                                                                            \
  }

  const char* Arow = (const char*)As + (mq + (lane & 15)) * 512;
  const int kb16 = (lane >> 4) * 16;
  const int swz = (lane & 7) << 4;

  // prologue: stage chunk 0
  LOAD_A(0);
  STAGE_B(0, 0);
  asm volatile("s_waitcnt vmcnt(0)" ::: "memory");
  WRITE_A();
  __syncthreads();

  for (int nc = 0; nc < 16; ++nc) {
    int cur = nc & 1, alt = cur ^ 1;
    if (nc < 15) {          // T14: issue next-chunk loads before compute
      LOAD_A(nc + 1);
      STAGE_B(alt, nc + 1);
    }
    {                        // compute chunk nc: 8 K-steps
      const char* Brow = (const char*)&Bs[cur][0] + (chalf + (lane & 15)) * 512;
#pragma unroll
      for (int ks = 0; ks < 8; ++ks) {
        int off = (ks * 64 + kb16) ^ swz;
        short8_t a = *(const short8_t*)(Arow + off);
        short8_t bb = *(const short8_t*)(Brow + off);
        acc = __builtin_amdgcn_mfma_f32_16x16x32_bf16(a, bb, acc, 0, 0, 0);
      }
    }
    __syncthreads();         // all waves done reading As
    if (nc < 15) {
      asm volatile("s_waitcnt vmcnt(0)" ::: "memory");
      WRITE_A();             // As <- chunk nc+1
    }
    __syncthreads();
  }

  // epilogue: D[row=m][col=c], col=lane&15, row=(lane>>4)*4+reg
  int mG = mt * 32 + mq + (lane >> 4) * 4;
  int cG = chalf + (lane & 15);
  float* outp = x1 + (size_t)(b * 256 + mG) * 512 + o * 32 + cG;
#pragma unroll
  for (int r = 0; r < 4; ++r) outp[(size_t)r * 512] = acc[r];
#undef LOAD_A
#undef STAGE_B
#undef WRITE_A
}

// ---------- old fp32 fallback main kernel (used only if ws too small)
__global__ __launch_bounds__(256) void main_kernel(const float* __restrict__ x,
                                                   const float* __restrict__ kb,
                                                   const float* __restrict__ Wk,
                                                   float* __restrict__ x1out) {
  __shared__ float lds[NC_ * 256];
  const int tid = threadIdx.x;
  const int bm = blockIdx.x;
  const int b = bm >> 8;
  const int c = tid & 31;
  const int o0 = tid >> 5;
  const int o1 = o0 + 8;
  float wkr[16];
  {
    const float4* w4 = (const float4*)(Wk + c * 16);
#pragma unroll
    for (int qq = 0; qq < 4; ++qq) {
      float4 v = w4[qq];
      wkr[qq * 4 + 0] = v.x; wkr[qq * 4 + 1] = v.y;
      wkr[qq * 4 + 2] = v.z; wkr[qq * 4 + 3] = v.w;
    }
  }
  const float* kbb = kb + (size_t)bm * 65536;
  const float* xb  = x + b * (N_ * O_ * CIN_);
  float acc0 = 0.f, acc1 = 0.f;
  for (int ch = 0; ch < N_ / NC_; ++ch) {
    __syncthreads();
    {
      const float* src = kbb + ch * (NC_ * 256) + tid * 4;
      float* dst = lds + tid * 4;
#pragma unroll
      for (int i = 0; i < 8; ++i) gload_lds16(dst + i * 1024, src + i * 1024);
    }
    __syncthreads();
    const float* xrow = xb + (ch * NC_) * (O_ * CIN_);
#pragma unroll 4
    for (int n = 0; n < NC_; ++n) {
      const float4* k0p = (const float4*)(lds + n * 256 + o0 * 16);
      const float4* k1p = (const float4*)(lds + n * 256 + o1 * 16);
      float s0 = 0.f, s1 = 0.f;
#pragma unroll
      for (int qq = 0; qq < 4; ++qq) {
        float4 a = k0p[qq];
        s0 += a.x * wkr[qq * 4] + a.y * wkr[qq * 4 + 1] + a.z * wkr[qq * 4 + 2] + a.w * wkr[qq * 4 + 3];
        float4 bq = k1p[qq];
        s1 += bq.x * wkr[qq * 4] + bq.y * wkr[qq * 4 + 1] + bq.z * wkr[qq * 4 + 2] + bq.w * wkr[qq * 4 + 3];
      }
      float xv0 = xrow[n * 512 + o0 * 32 + c];
      float xv1 = xrow[n * 512 + o1 * 32 + c];
      acc0 = fmaf(s0, xv0, acc0);
      acc1 = fmaf(s1, xv1, acc1);
    }
  }
  x1out[bm * 512 + o0 * 32 + c] = acc0;
  x1out[bm * 512 + o1 * 32 + c] = acc1;
}

// ---------- Kernel 4: out[bm, pd] = sum_oc x1[bm, oc] * fkT[oc, pd] + bias[pd&31]
__global__ __launch_bounds__(256) void fiber_kernel(const float* __restrict__ x1,
                                                    const float* __restrict__ fkT,
                                                    const float* __restrict__ bias,
                                                    float* __restrict__ out) {
  __shared__ float At[32][68];
  __shared__ float Bt[32][64];
  const int tid = threadIdx.x;
  const int bx = blockIdx.x & 7;
  const int by = blockIdx.x >> 3;
  const int tr = tid >> 4, tc = tid & 15;
  const int row0 = by * 64, col0 = bx * 64;
  float acc[4][4] = {};
  for (int kc = 0; kc < 512; kc += 32) {
    __syncthreads();
    {
      int r8 = tid >> 3, kq = tid & 7;
#pragma unroll
      for (int ii = 0; ii < 2; ++ii) {
        int r = r8 + ii * 32;
        float4 a = *(const float4*)(x1 + (row0 + r) * 512 + kc + kq * 4);
        At[kq * 4 + 0][r] = a.x; At[kq * 4 + 1][r] = a.y;
        At[kq * 4 + 2][r] = a.z; At[kq * 4 + 3][r] = a.w;
      }
#pragma unroll
      for (int ii = 0; ii < 2; ++ii) {
        int idx = tid + ii * 256;
        int k = idx >> 4, c4 = idx & 15;
        *(float4*)&Bt[k][c4 * 4] = *(const float4*)(fkT + (kc + k) * 512 + col0 + c4 * 4);
      }
    }
    __syncthreads();
#pragma unroll 8
    for (int k = 0; k < 32; ++k) {
      float4 av = *(const float4*)&At[k][tr * 4];
      float4 bv = *(const float4*)&Bt[k][tc * 4];
      float ar[4] = {av.x, av.y, av.z, av.w};
      float br[4] = {bv.x, bv.y, bv.z, bv.w};
#pragma unroll
      for (int i = 0; i < 4; ++i)
#pragma unroll
        for (int j = 0; j < 4; ++j)
          acc[i][j] = fmaf(ar[i], br[j], acc[i][j]);
    }
  }
  float4 bias4 = *(const float4*)(bias + ((tc * 4) & 31));
  float bb[4] = {bias4.x, bias4.y, bias4.z, bias4.w};
#pragma unroll
  for (int i = 0; i < 4; ++i) {
    float4 o4;
    o4.x = acc[i][0] + bb[0]; o4.y = acc[i][1] + bb[1];
    o4.z = acc[i][2] + bb[2]; o4.w = acc[i][3] + bb[3];
    *(float4*)(out + (row0 + tr * 4 + i) * 512 + col0 + tc * 4) = o4;
  }
}

extern "C" void kernel_launch(void* const* d_in, const int* in_sizes, int n_in,
                              void* d_out, int out_size, void* d_ws, size_t ws_size,
                              hipStream_t stream) {
  const float* x    = (const float*)d_in[0];  // [4,256,16,32]
  const float* kbas = (const float*)d_in[1];  // [4,256,256,16,16]
  const float* fb   = (const float*)d_in[2];  // [16,16,16]
  const float* Wk   = (const float*)d_in[3];  // [32,16]
  const float* Wf   = (const float*)d_in[4];  // [1024,16]
  const float* bias = (const float*)d_in[5];  // [32]
  float* out = (float*)d_out;                 // [4,256,16,32] f32

  float* fkT = (float*)d_ws;                       // 1 MB
  float* x1  = fkT + 262144;                       // 2 MB
  short* b2s = (short*)(x1 + 524288);              // 16.78 MB bf16
  const size_t need = 1048576 + 2097152 + 16777216;

  fk_kernel<<<256, 256, 0, stream>>>(fb, Wf, fkT);
  if (ws_size >= need) {
    b2_kernel<<<4096, 256, 0, stream>>>(x, Wk, b2s);
    gemm_kernel<<<512, 256, 0, stream>>>(kbas, b2s, x1);
  } else {
    main_kernel<<<1024, 256, 0, stream>>>(x, kbas, Wk, x1);
  }
  fiber_kernel<<<128, 256, 0, stream>>>(x1, fkT, bias, out);
}

// Round 3
// 120.445 us; speedup vs baseline: 1.5516x; 1.1747x over previous
//
#include <hip/hip_runtime.h>
#include <hip/hip_bf16.h>

typedef __attribute__((ext_vector_type(8))) short short8_t;   // 8 bf16
typedef __attribute__((ext_vector_type(4))) float floatx4;

__device__ __forceinline__ short bf16_of(float f) {
  __hip_bfloat16 h = __float2bfloat16(f);
  return __builtin_bit_cast(short, h);
}

__device__ __forceinline__ short8_t cvt8(float4 x, float4 y) {
  short8_t v;
  v[0] = bf16_of(x.x); v[1] = bf16_of(x.y); v[2] = bf16_of(x.z); v[3] = bf16_of(x.w);
  v[4] = bf16_of(y.x); v[5] = bf16_of(y.y); v[6] = bf16_of(y.z); v[7] = bf16_of(y.w);
  return v;
}

// ---------- Kernel 1: fkT[oc][pd] = sum_k fb[p,o,k] * Wf[d*32+c, k] / 1024
__global__ __launch_bounds__(256) void fk_kernel(const float* __restrict__ fb,
                                                 const float* __restrict__ Wf,
                                                 float* __restrict__ fkT) {
  int gid = blockIdx.x * 256 + threadIdx.x;
#pragma unroll
  for (int i = 0; i < 4; ++i) {
    int idx = gid + i * 65536;
    int pd = idx & 511;
    int oc = idx >> 9;
    int o = oc >> 5, c = oc & 31;
    int p = pd >> 5, d = pd & 31;
    const float4* fb4 = (const float4*)(fb + (p * 16 + o) * 16);
    const float4* wf4 = (const float4*)(Wf + (d * 32 + c) * 16);
    float s = 0.f;
#pragma unroll
    for (int q = 0; q < 4; ++q) {
      float4 a = fb4[q], w = wf4[q];
      s += a.x * w.x + a.y * w.y + a.z * w.z + a.w * w.w;
    }
    fkT[idx] = s * (1.0f / 1024.0f);
  }
}

// ---------- Kernel 2: barrier-free streaming MFMA.
// Per wave: output tile 16m x 32c for one (b,o). A read direct from global
// (f32 -> bf16 in reg); B fragment computed in reg: B[c,K=n*16+k] = x[b,n,o,c]*Wk[c,k].
// A-frag layout (refcheck-verified round 2): row = lane&15, k = (lane>>4)*8 + j.
__global__ __launch_bounds__(256) void gemm_direct(const float* __restrict__ kb,
                                                   const float* __restrict__ x,
                                                   const float* __restrict__ Wk,
                                                   float* __restrict__ x1) {
  const int tid = threadIdx.x;
  const int bid = blockIdx.x;          // 256 blocks
  const int bo = bid & 63;             // same-bo blocks -> same XCD (64 % 8 == 0)
  const int b = bo >> 4, o = bo & 15;
  const int wave = tid >> 6, lane = tid & 63;
  const int mt = (bid >> 6) * 4 + wave;   // m-tile [0,16), 16 rows each
  const int r = lane & 15, g = lane >> 4; // row/col-in-tile, k-group

  // A: KB[b, m, n, o, k]  elem offset = m*65536 + n*256 + o*16 + k
  // lane's K-step-0 elems: n = (g>>1), k = (g&1)*8 + j  (8 contiguous f32)
  const float* gA = kb + (size_t)((b * 256 + mt * 16 + r)) * 65536
                    + (g >> 1) * 256 + o * 16 + (g & 1) * 8;
  // x: [b, n, o, c]  offset = ((b*256+n)*16+o)*32 + c ; per lane n = (g>>1)
  const float* gx = x + ((size_t)(b * 256) * 16 + o) * 32 + (g >> 1) * 512 + r;

  // Wk rows r and r+16, k-slice (g&1)*8 .. +7  (8 f32 each) — the B weights
  float w0[8], w1[8];
  {
    const float4* p0 = (const float4*)(Wk + r * 16 + (g & 1) * 8);
    const float4* p1 = (const float4*)(Wk + (r + 16) * 16 + (g & 1) * 8);
    float4 a = p0[0], bq = p0[1], cq = p1[0], dq = p1[1];
    w0[0] = a.x; w0[1] = a.y; w0[2] = a.z; w0[3] = a.w;
    w0[4] = bq.x; w0[5] = bq.y; w0[6] = bq.z; w0[7] = bq.w;
    w1[0] = cq.x; w1[1] = cq.y; w1[2] = cq.z; w1[3] = cq.w;
    w1[4] = dq.x; w1[5] = dq.y; w1[6] = dq.z; w1[7] = dq.w;
  }

  floatx4 acc0 = {0.f, 0.f, 0.f, 0.f}, acc1 = {0.f, 0.f, 0.f, 0.f};

  // manual 2-stage pipeline over K (step = 32): named regs, no dynamic indexing
  float4 aAx, aAy, aBx, aBy;
  float xA0, xA1, xB0, xB1;

#define LOADF(sx, sy, v0, v1, kk_)                       \
  {                                                      \
    const float* pa = gA + (kk_) * 16;                   \
    sx = *(const float4*)pa;                             \
    sy = *(const float4*)(pa + 4);                       \
    const float* px = gx + (kk_) * 32;                   \
    v0 = px[0];                                          \
    v1 = px[16];                                         \
  }
#define COMPUTE(sx, sy, v0, v1)                          \
  {                                                      \
    short8_t afr = cvt8(sx, sy);                         \
    short8_t bf0, bf1;                                   \
    _Pragma("unroll") for (int j = 0; j < 8; ++j) {      \
      bf0[j] = bf16_of(v0 * w0[j]);                      \
      bf1[j] = bf16_of(v1 * w1[j]);                      \
    }                                                    \
    acc0 = __builtin_amdgcn_mfma_f32_16x16x32_bf16(afr, bf0, acc0, 0, 0, 0); \
    acc1 = __builtin_amdgcn_mfma_f32_16x16x32_bf16(afr, bf1, acc1, 0, 0, 0); \
  }

  LOADF(aAx, aAy, xA0, xA1, 0);
  for (int kk = 0; kk < 4096; kk += 64) {
    LOADF(aBx, aBy, xB0, xB1, kk + 32);
    COMPUTE(aAx, aAy, xA0, xA1);
    if (kk + 64 < 4096) LOADF(aAx, aAy, xA0, xA1, kk + 64);
    COMPUTE(aBx, aBy, xB0, xB1);
  }
#undef LOADF
#undef COMPUTE

  // C/D: col = lane&15, row = (lane>>4)*4 + reg  (refcheck-verified round 2)
  float* op = x1 + (size_t)(b * 256 + mt * 16 + g * 4) * 512 + o * 32 + r;
#pragma unroll
  for (int j = 0; j < 4; ++j) {
    op[(size_t)j * 512] = acc0[j];
    op[(size_t)j * 512 + 16] = acc1[j];
  }
}

// ---------- Kernel 3: out[bm, pd] = sum_oc x1[bm, oc] * fkT[oc, pd] + bias[pd&31]
__global__ __launch_bounds__(256) void fiber_kernel(const float* __restrict__ x1,
                                                    const float* __restrict__ fkT,
                                                    const float* __restrict__ bias,
                                                    float* __restrict__ out) {
  __shared__ float At[32][68];
  __shared__ float Bt[32][64];
  const int tid = threadIdx.x;
  const int bx = blockIdx.x & 7;
  const int by = blockIdx.x >> 3;
  const int tr = tid >> 4, tc = tid & 15;
  const int row0 = by * 64, col0 = bx * 64;
  float acc[4][4] = {};
  for (int kc = 0; kc < 512; kc += 32) {
    __syncthreads();
    {
      int r8 = tid >> 3, kq = tid & 7;
#pragma unroll
      for (int ii = 0; ii < 2; ++ii) {
        int rr = r8 + ii * 32;
        float4 a = *(const float4*)(x1 + (row0 + rr) * 512 + kc + kq * 4);
        At[kq * 4 + 0][rr] = a.x; At[kq * 4 + 1][rr] = a.y;
        At[kq * 4 + 2][rr] = a.z; At[kq * 4 + 3][rr] = a.w;
      }
#pragma unroll
      for (int ii = 0; ii < 2; ++ii) {
        int idx = tid + ii * 256;
        int k = idx >> 4, c4 = idx & 15;
        *(float4*)&Bt[k][c4 * 4] = *(const float4*)(fkT + (kc + k) * 512 + col0 + c4 * 4);
      }
    }
    __syncthreads();
#pragma unroll 8
    for (int k = 0; k < 32; ++k) {
      float4 av = *(const float4*)&At[k][tr * 4];
      float4 bv = *(const float4*)&Bt[k][tc * 4];
      float ar[4] = {av.x, av.y, av.z, av.w};
      float br[4] = {bv.x, bv.y, bv.z, bv.w};
#pragma unroll
      for (int i = 0; i < 4; ++i)
#pragma unroll
        for (int j = 0; j < 4; ++j)
          acc[i][j] = fmaf(ar[i], br[j], acc[i][j]);
    }
  }
  float4 bias4 = *(const float4*)(bias + ((tc * 4) & 31));
  float bb[4] = {bias4.x, bias4.y, bias4.z, bias4.w};
#pragma unroll
  for (int i = 0; i < 4; ++i) {
    float4 o4;
    o4.x = acc[i][0] + bb[0]; o4.y = acc[i][1] + bb[1];
    o4.z = acc[i][2] + bb[2]; o4.w = acc[i][3] + bb[3];
    *(float4*)(out + (row0 + tr * 4 + i) * 512 + col0 + tc * 4) = o4;
  }
}

extern "C" void kernel_launch(void* const* d_in, const int* in_sizes, int n_in,
                              void* d_out, int out_size, void* d_ws, size_t ws_size,
                              hipStream_t stream) {
  const float* x    = (const float*)d_in[0];  // [4,256,16,32]
  const float* kbas = (const float*)d_in[1];  // [4,256,256,16,16]
  const float* fb   = (const float*)d_in[2];  // [16,16,16]
  const float* Wk   = (const float*)d_in[3];  // [32,16]
  const float* Wf   = (const float*)d_in[4];  // [1024,16]
  const float* bias = (const float*)d_in[5];  // [32]
  float* out = (float*)d_out;                 // [4,256,16,32] f32

  float* fkT = (float*)d_ws;        // 1 MB
  float* x1  = fkT + 262144;        // 2 MB

  fk_kernel<<<256, 256, 0, stream>>>(fb, Wf, fkT);
  gemm_direct<<<256, 256, 0, stream>>>(kbas, x, Wk, x1);
  fiber_kernel<<<128, 256, 0, stream>>>(x1, fkT, bias, out);
}

// Round 4
// 106.107 us; speedup vs baseline: 1.7613x; 1.1351x over previous
//
#include <hip/hip_runtime.h>
#include <hip/hip_bf16.h>

typedef __attribute__((ext_vector_type(8))) short short8_t;   // 8 bf16
typedef __attribute__((ext_vector_type(4))) float floatx4;

__device__ __forceinline__ short bf16_of(float f) {
  __hip_bfloat16 h = __float2bfloat16(f);
  return __builtin_bit_cast(short, h);
}

__device__ __forceinline__ short8_t cvt8(float4 x, float4 y) {
  short8_t v;
  v[0] = bf16_of(x.x); v[1] = bf16_of(x.y); v[2] = bf16_of(x.z); v[3] = bf16_of(x.w);
  v[4] = bf16_of(y.x); v[5] = bf16_of(y.y); v[6] = bf16_of(y.z); v[7] = bf16_of(y.w);
  return v;
}

// ---------- Kernel 1: fkT[oc][pd] = sum_k fb[p,o,k] * Wf[d*32+c, k] / 1024
__global__ __launch_bounds__(256) void fk_kernel(const float* __restrict__ fb,
                                                 const float* __restrict__ Wf,
                                                 float* __restrict__ fkT) {
  int gid = blockIdx.x * 256 + threadIdx.x;
#pragma unroll
  for (int i = 0; i < 4; ++i) {
    int idx = gid + i * 65536;
    int pd = idx & 511;
    int oc = idx >> 9;
    int o = oc >> 5, c = oc & 31;
    int p = pd >> 5, d = pd & 31;
    const float4* fb4 = (const float4*)(fb + (p * 16 + o) * 16);
    const float4* wf4 = (const float4*)(Wf + (d * 32 + c) * 16);
    float s = 0.f;
#pragma unroll
    for (int q = 0; q < 4; ++q) {
      float4 a = fb4[q], w = wf4[q];
      s += a.x * w.x + a.y * w.y + a.z * w.z + a.w * w.w;
    }
    fkT[idx] = s * (1.0f / 1024.0f);
  }
}

// ---------- Kernel 2: barrier-free streaming MFMA, split-K x4.
// bid = bo*16 + mtg*4 + ks  (bo = b*16+o). Wave w handles m-tile mt = mtg*4+w,
// K range [ks*1024, ks*1024+1024). Partial C written to slice x1p + ks*524288.
// Blocks sharing A cache lines (o, o+1) differ by bid 16 -> same XCD (%8).
__global__ __launch_bounds__(256) void gemm_split(const float* __restrict__ kb,
                                                  const float* __restrict__ x,
                                                  const float* __restrict__ Wk,
                                                  float* __restrict__ x1p) {
  const int tid = threadIdx.x;
  const int bid = blockIdx.x;              // 1024 blocks
  const int bo = bid >> 4;                 // [0,64)
  const int mtg = (bid >> 2) & 3;
  const int ks = bid & 3;
  const int b = bo >> 4, o = bo & 15;
  const int wave = tid >> 6, lane = tid & 63;
  const int mt = mtg * 4 + wave;           // [0,16)
  const int r = lane & 15, g = lane >> 4;

  // A: KB[b, m, n, o, k]  elem = m*65536 + n*256 + o*16 + k ; n = K>>4, k = K&15
  const float* gA = kb + (size_t)(b * 256 + mt * 16 + r) * 65536
                    + (ks * 64 + (g >> 1)) * 256 + o * 16 + (g & 1) * 8;
  // x[b,n,o,c]: elem = ((b*256+n)*16+o)*32 + c
  const float* gx = x + ((size_t)(b * 256) * 16 + o) * 32
                    + (size_t)(ks * 64 + (g >> 1)) * 512 + r;

  float w0[8], w1[8];
  {
    const float4* p0 = (const float4*)(Wk + r * 16 + (g & 1) * 8);
    const float4* p1 = (const float4*)(Wk + (r + 16) * 16 + (g & 1) * 8);
    float4 a = p0[0], bq = p0[1], cq = p1[0], dq = p1[1];
    w0[0] = a.x; w0[1] = a.y; w0[2] = a.z; w0[3] = a.w;
    w0[4] = bq.x; w0[5] = bq.y; w0[6] = bq.z; w0[7] = bq.w;
    w1[0] = cq.x; w1[1] = cq.y; w1[2] = cq.z; w1[3] = cq.w;
    w1[4] = dq.x; w1[5] = dq.y; w1[6] = dq.z; w1[7] = dq.w;
  }

  floatx4 acc0 = {0.f, 0.f, 0.f, 0.f}, acc1 = {0.f, 0.f, 0.f, 0.f};
  float4 aAx, aAy, aBx, aBy;
  float xA0, xA1, xB0, xB1;

#define LOADF(sx, sy, v0, v1, kk_)                       \
  {                                                      \
    const float* pa = gA + (size_t)(kk_) * 16;           \
    sx = *(const float4*)pa;                             \
    sy = *(const float4*)(pa + 4);                       \
    const float* px = gx + (size_t)(kk_) * 32;           \
    v0 = px[0];                                          \
    v1 = px[16];                                         \
  }
#define COMPUTE(sx, sy, v0, v1)                          \
  {                                                      \
    short8_t afr = cvt8(sx, sy);                         \
    short8_t bf0, bf1;                                   \
    _Pragma("unroll") for (int j = 0; j < 8; ++j) {      \
      bf0[j] = bf16_of(v0 * w0[j]);                      \
      bf1[j] = bf16_of(v1 * w1[j]);                      \
    }                                                    \
    acc0 = __builtin_amdgcn_mfma_f32_16x16x32_bf16(afr, bf0, acc0, 0, 0, 0); \
    acc1 = __builtin_amdgcn_mfma_f32_16x16x32_bf16(afr, bf1, acc1, 0, 0, 0); \
  }

  LOADF(aAx, aAy, xA0, xA1, 0);
  for (int kk = 0; kk < 1024; kk += 64) {
    LOADF(aBx, aBy, xB0, xB1, kk + 32);
    COMPUTE(aAx, aAy, xA0, xA1);
    if (kk + 64 < 1024) LOADF(aAx, aAy, xA0, xA1, kk + 64);
    COMPUTE(aBx, aBy, xB0, xB1);
  }
#undef LOADF
#undef COMPUTE

  // C/D: col = lane&15, row = (lane>>4)*4 + reg
  float* op = x1p + (size_t)ks * 524288
              + (size_t)(b * 256 + mt * 16 + g * 4) * 512 + o * 32 + r;
#pragma unroll
  for (int j = 0; j < 4; ++j) {
    op[(size_t)j * 512] = acc0[j];
    op[(size_t)j * 512 + 16] = acc1[j];
  }
}

// ---------- Kernel 3: out[bm, pd] = sum_oc (Σ_ks x1p[ks][bm,oc]) * fkT[oc,pd] + bias
template <int NS>
__global__ __launch_bounds__(256) void fiber_kernel(const float* __restrict__ x1p,
                                                    const float* __restrict__ fkT,
                                                    const float* __restrict__ bias,
                                                    float* __restrict__ out) {
  __shared__ float At[32][68];
  __shared__ float Bt[32][64];
  const int tid = threadIdx.x;
  const int bx = blockIdx.x & 7;
  const int by = blockIdx.x >> 3;
  const int tr = tid >> 4, tc = tid & 15;
  const int row0 = by * 64, col0 = bx * 64;
  float acc[4][4] = {};
  for (int kc = 0; kc < 512; kc += 32) {
    __syncthreads();
    {
      int r8 = tid >> 3, kq = tid & 7;
#pragma unroll
      for (int ii = 0; ii < 2; ++ii) {
        int rr = r8 + ii * 32;
        size_t off = (size_t)(row0 + rr) * 512 + kc + kq * 4;
        float4 a = *(const float4*)(x1p + off);
#pragma unroll
        for (int s = 1; s < NS; ++s) {
          float4 a2 = *(const float4*)(x1p + (size_t)s * 524288 + off);
          a.x += a2.x; a.y += a2.y; a.z += a2.z; a.w += a2.w;
        }
        At[kq * 4 + 0][rr] = a.x; At[kq * 4 + 1][rr] = a.y;
        At[kq * 4 + 2][rr] = a.z; At[kq * 4 + 3][rr] = a.w;
      }
#pragma unroll
      for (int ii = 0; ii < 2; ++ii) {
        int idx = tid + ii * 256;
        int k = idx >> 4, c4 = idx & 15;
        *(float4*)&Bt[k][c4 * 4] = *(const float4*)(fkT + (kc + k) * 512 + col0 + c4 * 4);
      }
    }
    __syncthreads();
#pragma unroll 8
    for (int k = 0; k < 32; ++k) {
      float4 av = *(const float4*)&At[k][tr * 4];
      float4 bv = *(const float4*)&Bt[k][tc * 4];
      float ar[4] = {av.x, av.y, av.z, av.w};
      float br[4] = {bv.x, bv.y, bv.z, bv.w};
#pragma unroll
      for (int i = 0; i < 4; ++i)
#pragma unroll
        for (int j = 0; j < 4; ++j)
          acc[i][j] = fmaf(ar[i], br[j], acc[i][j]);
    }
  }
  float4 bias4 = *(const float4*)(bias + ((tc * 4) & 31));
  float bb[4] = {bias4.x, bias4.y, bias4.z, bias4.w};
#pragma unroll
  for (int i = 0; i < 4; ++i) {
    float4 o4;
    o4.x = acc[i][0] + bb[0]; o4.y = acc[i][1] + bb[1];
    o4.z = acc[i][2] + bb[2]; o4.w = acc[i][3] + bb[3];
    *(float4*)(out + (row0 + tr * 4 + i) * 512 + col0 + tc * 4) = o4;
  }
}

// ---------- fallback: single-pass (only if ws too small for partials)
__global__ __launch_bounds__(256) void gemm_direct(const float* __restrict__ kb,
                                                   const float* __restrict__ x,
                                                   const float* __restrict__ Wk,
                                                   float* __restrict__ x1) {
  const int tid = threadIdx.x;
  const int bid = blockIdx.x;
  const int bo = bid & 63;
  const int b = bo >> 4, o = bo & 15;
  const int wave = tid >> 6, lane = tid & 63;
  const int mt = (bid >> 6) * 4 + wave;
  const int r = lane & 15, g = lane >> 4;
  const float* gA = kb + (size_t)(b * 256 + mt * 16 + r) * 65536
                    + (g >> 1) * 256 + o * 16 + (g & 1) * 8;
  const float* gx = x + ((size_t)(b * 256) * 16 + o) * 32 + (g >> 1) * 512 + r;
  float w0[8], w1[8];
  {
    const float4* p0 = (const float4*)(Wk + r * 16 + (g & 1) * 8);
    const float4* p1 = (const float4*)(Wk + (r + 16) * 16 + (g & 1) * 8);
    float4 a = p0[0], bq = p0[1], cq = p1[0], dq = p1[1];
    w0[0] = a.x; w0[1] = a.y; w0[2] = a.z; w0[3] = a.w;
    w0[4] = bq.x; w0[5] = bq.y; w0[6] = bq.z; w0[7] = bq.w;
    w1[0] = cq.x; w1[1] = cq.y; w1[2] = cq.z; w1[3] = cq.w;
    w1[4] = dq.x; w1[5] = dq.y; w1[6] = dq.z; w1[7] = dq.w;
  }
  floatx4 acc0 = {0.f, 0.f, 0.f, 0.f}, acc1 = {0.f, 0.f, 0.f, 0.f};
  float4 aAx, aAy, aBx, aBy;
  float xA0, xA1, xB0, xB1;
#define LOADF(sx, sy, v0, v1, kk_)                       \
  {                                                      \
    const float* pa = gA + (size_t)(kk_) * 16;           \
    sx = *(const float4*)pa;                             \
    sy = *(const float4*)(pa + 4);                       \
    const float* px = gx + (size_t)(kk_) * 32;           \
    v0 = px[0];                                          \
    v1 = px[16];                                         \
  }
#define COMPUTE(sx, sy, v0, v1)                          \
  {                                                      \
    short8_t afr = cvt8(sx, sy);                         \
    short8_t bf0, bf1;                                   \
    _Pragma("unroll") for (int j = 0; j < 8; ++j) {      \
      bf0[j] = bf16_of(v0 * w0[j]);                      \
      bf1[j] = bf16_of(v1 * w1[j]);                      \
    }                                                    \
    acc0 = __builtin_amdgcn_mfma_f32_16x16x32_bf16(afr, bf0, acc0, 0, 0, 0); \
    acc1 = __builtin_amdgcn_mfma_f32_16x16x32_bf16(afr, bf1, acc1, 0, 0, 0); \
  }
  LOADF(aAx, aAy, xA0, xA1, 0);
  for (int kk = 0; kk < 4096; kk += 64) {
    LOADF(aBx, aBy, xB0, xB1, kk + 32);
    COMPUTE(aAx, aAy, xA0, xA1);
    if (kk + 64 < 4096) LOADF(aAx, aAy, xA0, xA1, kk + 64);
    COMPUTE(aBx, aBy, xB0, xB1);
  }
#undef LOADF
#undef COMPUTE
  float* op = x1 + (size_t)(b * 256 + mt * 16 + g * 4) * 512 + o * 32 + r;
#pragma unroll
  for (int j = 0; j < 4; ++j) {
    op[(size_t)j * 512] = acc0[j];
    op[(size_t)j * 512 + 16] = acc1[j];
  }
}

extern "C" void kernel_launch(void* const* d_in, const int* in_sizes, int n_in,
                              void* d_out, int out_size, void* d_ws, size_t ws_size,
                              hipStream_t stream) {
  const float* x    = (const float*)d_in[0];  // [4,256,16,32]
  const float* kbas = (const float*)d_in[1];  // [4,256,256,16,16]
  const float* fb   = (const float*)d_in[2];  // [16,16,16]
  const float* Wk   = (const float*)d_in[3];  // [32,16]
  const float* Wf   = (const float*)d_in[4];  // [1024,16]
  const float* bias = (const float*)d_in[5];  // [32]
  float* out = (float*)d_out;                 // [4,256,16,32] f32

  float* fkT = (float*)d_ws;          // 1 MB
  float* x1p = fkT + 262144;          // 4 x 2 MB partial slices
  const size_t need = (262144 + 4 * 524288) * sizeof(float);

  fk_kernel<<<256, 256, 0, stream>>>(fb, Wf, fkT);
  if (ws_size >= need) {
    gemm_split<<<1024, 256, 0, stream>>>(kbas, x, Wk, x1p);
    fiber_kernel<4><<<128, 256, 0, stream>>>(x1p, fkT, bias, out);
  } else {
    gemm_direct<<<256, 256, 0, stream>>>(kbas, x, Wk, x1p);
    fiber_kernel<1><<<128, 256, 0, stream>>>(x1p, fkT, bias, out);
  }
}

// Round 5
// 101.908 us; speedup vs baseline: 1.8339x; 1.0412x over previous
//
#include <hip/hip_runtime.h>
#include <hip/hip_bf16.h>

typedef __attribute__((ext_vector_type(8))) short short8_t;   // 8 bf16
typedef __attribute__((ext_vector_type(4))) float floatx4;

__device__ __forceinline__ short bf16_of(float f) {
  __hip_bfloat16 h = __float2bfloat16(f);
  return __builtin_bit_cast(short, h);
}

__device__ __forceinline__ short8_t cvt8(float4 x, float4 y) {
  short8_t v;
  v[0] = bf16_of(x.x); v[1] = bf16_of(x.y); v[2] = bf16_of(x.z); v[3] = bf16_of(x.w);
  v[4] = bf16_of(y.x); v[5] = bf16_of(y.y); v[6] = bf16_of(y.z); v[7] = bf16_of(y.w);
  return v;
}

// ---------- Kernel 1: fkT[oc][pd] = sum_k fb[p,o,k] * Wf[d*32+c, k] / 1024
__global__ __launch_bounds__(256) void fk_kernel(const float* __restrict__ fb,
                                                 const float* __restrict__ Wf,
                                                 float* __restrict__ fkT) {
  int gid = blockIdx.x * 256 + threadIdx.x;
#pragma unroll
  for (int i = 0; i < 4; ++i) {
    int idx = gid + i * 65536;
    int pd = idx & 511;
    int oc = idx >> 9;
    int o = oc >> 5, c = oc & 31;
    int p = pd >> 5, d = pd & 31;
    const float4* fb4 = (const float4*)(fb + (p * 16 + o) * 16);
    const float4* wf4 = (const float4*)(Wf + (d * 32 + c) * 16);
    float s = 0.f;
#pragma unroll
    for (int q = 0; q < 4; ++q) {
      float4 a = fb4[q], w = wf4[q];
      s += a.x * w.x + a.y * w.y + a.z * w.z + a.w * w.w;
    }
    fkT[idx] = s * (1.0f / 1024.0f);
  }
}

// ---------- Kernel 2: o-pair streaming MFMA, split-K x8, full-128B-line consumption.
// bid = ((b*8+op)*4+mtg)*8+ks. Wave computes 16m x 32c for BOTH o0=2*op and o1=o0+1.
// Per K-step (2 n): load1 = line(n0) quarter g, load2 = line(n1) quarter g^2.
// af_o0 = (g<2 ? a1 : a2); af_o1 = shfl_xor(g<2 ? a2 : a1, 32).
__global__ __launch_bounds__(256) void gemm_pair(const float* __restrict__ kb,
                                                 const float* __restrict__ x,
                                                 const float* __restrict__ Wk,
                                                 float* __restrict__ x1p) {
  const int tid = threadIdx.x;
  const int bid = blockIdx.x;              // 1024 blocks
  const int ks  = bid & 7;
  const int mtg = (bid >> 3) & 3;
  const int op  = (bid >> 5) & 7;
  const int b   = bid >> 8;
  const int wave = tid >> 6, lane = tid & 63;
  const int mt = mtg * 4 + wave;           // [0,16)
  const int r = lane & 15, g = lane >> 4;

  // A: elem = (b*256+m)*65536 + n*256 + op*32 + quarter*8 ; per t: n += 2 -> +512
  const size_t rowbase = (size_t)(b * 256 + mt * 16 + r) * 65536
                         + (size_t)(ks * 32) * 256 + op * 32;
  const float* gA1 = kb + rowbase + g * 8;               // n0-line, quarter g
  const float* gA2 = kb + rowbase + 256 + (g ^ 2) * 8;   // n1-line, quarter g^2
  // x: elem = ((b*256+n)*16+o0)*32 + c ; o stride 32, per t: +1024
  const float* gx = x + ((size_t)(b * 256 + ks * 32 + (g >> 1)) * 16 + 2 * op) * 32 + r;

  float w0[8], w1[8];   // Wk[r, (g&1)*8+j], Wk[r+16, (g&1)*8+j]
  {
    const float4* p0 = (const float4*)(Wk + r * 16 + (g & 1) * 8);
    const float4* p1 = (const float4*)(Wk + (r + 16) * 16 + (g & 1) * 8);
    float4 a = p0[0], bq = p0[1], cq = p1[0], dq = p1[1];
    w0[0] = a.x; w0[1] = a.y; w0[2] = a.z; w0[3] = a.w;
    w0[4] = bq.x; w0[5] = bq.y; w0[6] = bq.z; w0[7] = bq.w;
    w1[0] = cq.x; w1[1] = cq.y; w1[2] = cq.z; w1[3] = cq.w;
    w1[4] = dq.x; w1[5] = dq.y; w1[6] = dq.z; w1[7] = dq.w;
  }

  floatx4 acc00 = {0.f, 0.f, 0.f, 0.f}, acc01 = {0.f, 0.f, 0.f, 0.f};
  floatx4 acc10 = {0.f, 0.f, 0.f, 0.f}, acc11 = {0.f, 0.f, 0.f, 0.f};

  const bool lo = (g < 2);
  float4 A1xA, A1yA, A2xA, A2yA, xvA;
  float4 A1xB, A1yB, A2xB, A2yB, xvB;

#define LOADF(s1x, s1y, s2x, s2y, xv, t_)                \
  {                                                      \
    const float* p1_ = gA1 + (size_t)(t_) * 512;         \
    s1x = *(const float4*)p1_;                           \
    s1y = *(const float4*)(p1_ + 4);                     \
    const float* p2_ = gA2 + (size_t)(t_) * 512;         \
    s2x = *(const float4*)p2_;                           \
    s2y = *(const float4*)(p2_ + 4);                     \
    const float* px_ = gx + (size_t)(t_) * 1024;         \
    xv.x = px_[0];                                       \
    xv.y = px_[16];                                      \
    xv.z = px_[32];                                      \
    xv.w = px_[48];                                      \
  }
#define COMPUTE(s1x, s1y, s2x, s2y, xv)                                          \
  {                                                                              \
    short8_t a1 = cvt8(s1x, s1y);                                                \
    short8_t a2 = cvt8(s2x, s2y);                                                \
    short8_t af0 = lo ? a1 : a2;                                                 \
    short8_t pr  = lo ? a2 : a1;                                                 \
    int4 pi = __builtin_bit_cast(int4, pr);                                      \
    pi.x = __shfl_xor(pi.x, 32);                                                 \
    pi.y = __shfl_xor(pi.y, 32);                                                 \
    pi.z = __shfl_xor(pi.z, 32);                                                 \
    pi.w = __shfl_xor(pi.w, 32);                                                 \
    short8_t af1 = __builtin_bit_cast(short8_t, pi);                             \
    short8_t b00, b01, b10, b11;                                                 \
    _Pragma("unroll") for (int j = 0; j < 8; ++j) {                              \
      b00[j] = bf16_of(xv.x * w0[j]);                                            \
      b01[j] = bf16_of(xv.y * w1[j]);                                            \
      b10[j] = bf16_of(xv.z * w0[j]);                                            \
      b11[j] = bf16_of(xv.w * w1[j]);                                            \
    }                                                                            \
    acc00 = __builtin_amdgcn_mfma_f32_16x16x32_bf16(af0, b00, acc00, 0, 0, 0);   \
    acc01 = __builtin_amdgcn_mfma_f32_16x16x32_bf16(af0, b01, acc01, 0, 0, 0);   \
    acc10 = __builtin_amdgcn_mfma_f32_16x16x32_bf16(af1, b10, acc10, 0, 0, 0);   \
    acc11 = __builtin_amdgcn_mfma_f32_16x16x32_bf16(af1, b11, acc11, 0, 0, 0);   \
  }

  LOADF(A1xA, A1yA, A2xA, A2yA, xvA, 0);
  for (int t = 0; t < 16; t += 2) {
    LOADF(A1xB, A1yB, A2xB, A2yB, xvB, t + 1);
    COMPUTE(A1xA, A1yA, A2xA, A2yA, xvA);
    if (t + 2 < 16) LOADF(A1xA, A1yA, A2xA, A2yA, xvA, t + 2);
    COMPUTE(A1xB, A1yB, A2xB, A2yB, xvB);
  }
#undef LOADF
#undef COMPUTE

  // C/D: col = lane&15 (=r), row = g*4 + reg
  float* base = x1p + (size_t)ks * 524288
                + (size_t)(b * 256 + mt * 16 + g * 4) * 512 + op * 64 + r;
#pragma unroll
  for (int j = 0; j < 4; ++j) {
    base[(size_t)j * 512]      = acc00[j];
    base[(size_t)j * 512 + 16] = acc01[j];
    base[(size_t)j * 512 + 32] = acc10[j];
    base[(size_t)j * 512 + 48] = acc11[j];
  }
}

// ---------- Kernel 3: x1 = sum of 8 partial slices
__global__ __launch_bounds__(256) void reduce8(const float* __restrict__ x1p,
                                               float* __restrict__ x1) {
  int i = blockIdx.x * 256 + threadIdx.x;    // 131072 float4s
  float4 s = ((const float4*)x1p)[i];
#pragma unroll
  for (int sl = 1; sl < 8; ++sl) {
    float4 a = ((const float4*)(x1p + (size_t)sl * 524288))[i];
    s.x += a.x; s.y += a.y; s.z += a.z; s.w += a.w;
  }
  ((float4*)x1)[i] = s;
}

// ---------- Kernel 4: out[bm, pd] = sum_oc x1[bm,oc] * fkT[oc,pd] + bias[pd&31]
__global__ __launch_bounds__(256) void fiber_kernel(const float* __restrict__ x1,
                                                    const float* __restrict__ fkT,
                                                    const float* __restrict__ bias,
                                                    float* __restrict__ out) {
  __shared__ float At[32][68];
  __shared__ float Bt[32][64];
  const int tid = threadIdx.x;
  const int bx = blockIdx.x & 7;
  const int by = blockIdx.x >> 3;
  const int tr = tid >> 4, tc = tid & 15;
  const int row0 = by * 64, col0 = bx * 64;
  float acc[4][4] = {};
  for (int kc = 0; kc < 512; kc += 32) {
    __syncthreads();
    {
      int r8 = tid >> 3, kq = tid & 7;
#pragma unroll
      for (int ii = 0; ii < 2; ++ii) {
        int rr = r8 + ii * 32;
        float4 a = *(const float4*)(x1 + (size_t)(row0 + rr) * 512 + kc + kq * 4);
        At[kq * 4 + 0][rr] = a.x; At[kq * 4 + 1][rr] = a.y;
        At[kq * 4 + 2][rr] = a.z; At[kq * 4 + 3][rr] = a.w;
      }
#pragma unroll
      for (int ii = 0; ii < 2; ++ii) {
        int idx = tid + ii * 256;
        int k = idx >> 4, c4 = idx & 15;
        *(float4*)&Bt[k][c4 * 4] = *(const float4*)(fkT + (kc + k) * 512 + col0 + c4 * 4);
      }
    }
    __syncthreads();
#pragma unroll 8
    for (int k = 0; k < 32; ++k) {
      float4 av = *(const float4*)&At[k][tr * 4];
      float4 bv = *(const float4*)&Bt[k][tc * 4];
      float ar[4] = {av.x, av.y, av.z, av.w};
      float br[4] = {bv.x, bv.y, bv.z, bv.w};
#pragma unroll
      for (int i = 0; i < 4; ++i)
#pragma unroll
        for (int j = 0; j < 4; ++j)
          acc[i][j] = fmaf(ar[i], br[j], acc[i][j]);
    }
  }
  float4 bias4 = *(const float4*)(bias + ((tc * 4) & 31));
  float bb[4] = {bias4.x, bias4.y, bias4.z, bias4.w};
#pragma unroll
  for (int i = 0; i < 4; ++i) {
    float4 o4;
    o4.x = acc[i][0] + bb[0]; o4.y = acc[i][1] + bb[1];
    o4.z = acc[i][2] + bb[2]; o4.w = acc[i][3] + bb[3];
    *(float4*)(out + (size_t)(row0 + tr * 4 + i) * 512 + col0 + tc * 4) = o4;
  }
}

// ---------- fallback: single-pass direct (only if ws too small)
__global__ __launch_bounds__(256) void gemm_direct(const float* __restrict__ kb,
                                                   const float* __restrict__ x,
                                                   const float* __restrict__ Wk,
                                                   float* __restrict__ x1) {
  const int tid = threadIdx.x;
  const int bid = blockIdx.x;
  const int bo = bid & 63;
  const int b = bo >> 4, o = bo & 15;
  const int wave = tid >> 6, lane = tid & 63;
  const int mt = (bid >> 6) * 4 + wave;
  const int r = lane & 15, g = lane >> 4;
  const float* gA = kb + (size_t)(b * 256 + mt * 16 + r) * 65536
                    + (g >> 1) * 256 + o * 16 + (g & 1) * 8;
  const float* gx = x + ((size_t)(b * 256) * 16 + o) * 32 + (g >> 1) * 512 + r;
  float w0[8], w1[8];
  {
    const float4* p0 = (const float4*)(Wk + r * 16 + (g & 1) * 8);
    const float4* p1 = (const float4*)(Wk + (r + 16) * 16 + (g & 1) * 8);
    float4 a = p0[0], bq = p0[1], cq = p1[0], dq = p1[1];
    w0[0] = a.x; w0[1] = a.y; w0[2] = a.z; w0[3] = a.w;
    w0[4] = bq.x; w0[5] = bq.y; w0[6] = bq.z; w0[7] = bq.w;
    w1[0] = cq.x; w1[1] = cq.y; w1[2] = cq.z; w1[3] = cq.w;
    w1[4] = dq.x; w1[5] = dq.y; w1[6] = dq.z; w1[7] = dq.w;
  }
  floatx4 acc0 = {0.f, 0.f, 0.f, 0.f}, acc1 = {0.f, 0.f, 0.f, 0.f};
  float4 aAx, aAy, aBx, aBy;
  float xA0, xA1, xB0, xB1;
#define LOADF(sx, sy, v0, v1, kk_)                       \
  {                                                      \
    const float* pa = gA + (size_t)(kk_) * 16;           \
    sx = *(const float4*)pa;                             \
    sy = *(const float4*)(pa + 4);                       \
    const float* px = gx + (size_t)(kk_) * 32;           \
    v0 = px[0];                                          \
    v1 = px[16];                                         \
  }
#define COMPUTE(sx, sy, v0, v1)                          \
  {                                                      \
    short8_t afr = cvt8(sx, sy);                         \
    short8_t bf0, bf1;                                   \
    _Pragma("unroll") for (int j = 0; j < 8; ++j) {      \
      bf0[j] = bf16_of(v0 * w0[j]);                      \
      bf1[j] = bf16_of(v1 * w1[j]);                      \
    }                                                    \
    acc0 = __builtin_amdgcn_mfma_f32_16x16x32_bf16(afr, bf0, acc0, 0, 0, 0); \
    acc1 = __builtin_amdgcn_mfma_f32_16x16x32_bf16(afr, bf1, acc1, 0, 0, 0); \
  }
  LOADF(aAx, aAy, xA0, xA1, 0);
  for (int kk = 0; kk < 4096; kk += 64) {
    LOADF(aBx, aBy, xB0, xB1, kk + 32);
    COMPUTE(aAx, aAy, xA0, xA1);
    if (kk + 64 < 4096) LOADF(aAx, aAy, xA0, xA1, kk + 64);
    COMPUTE(aBx, aBy, xB0, xB1);
  }
#undef LOADF
#undef COMPUTE
  float* op = x1 + (size_t)(b * 256 + mt * 16 + g * 4) * 512 + o * 32 + r;
#pragma unroll
  for (int j = 0; j < 4; ++j) {
    op[(size_t)j * 512] = acc0[j];
    op[(size_t)j * 512 + 16] = acc1[j];
  }
}

extern "C" void kernel_launch(void* const* d_in, const int* in_sizes, int n_in,
                              void* d_out, int out_size, void* d_ws, size_t ws_size,
                              hipStream_t stream) {
  const float* x    = (const float*)d_in[0];  // [4,256,16,32]
  const float* kbas = (const float*)d_in[1];  // [4,256,256,16,16]
  const float* fb   = (const float*)d_in[2];  // [16,16,16]
  const float* Wk   = (const float*)d_in[3];  // [32,16]
  const float* Wf   = (const float*)d_in[4];  // [1024,16]
  const float* bias = (const float*)d_in[5];  // [32]
  float* out = (float*)d_out;                 // [4,256,16,32] f32

  float* fkT = (float*)d_ws;          // 1 MB
  float* x1  = fkT + 262144;          // 2 MB
  float* x1p = x1 + 524288;           // 8 x 2 MB partial slices
  const size_t need = (262144 + 524288 + 8 * 524288) * sizeof(float);

  fk_kernel<<<256, 256, 0, stream>>>(fb, Wf, fkT);
  if (ws_size >= need) {
    gemm_pair<<<1024, 256, 0, stream>>>(kbas, x, Wk, x1p);
    reduce8<<<512, 256, 0, stream>>>(x1p, x1);
  } else {
    gemm_direct<<<256, 256, 0, stream>>>(kbas, x, Wk, x1);
  }
  fiber_kernel<<<128, 256, 0, stream>>>(x1, fkT, bias, out);
}

// Round 6
// 95.781 us; speedup vs baseline: 1.9512x; 1.0640x over previous
//
#include <hip/hip_runtime.h>
#include <hip/hip_bf16.h>

typedef __attribute__((ext_vector_type(8))) short short8_t;   // 8 bf16
typedef __attribute__((ext_vector_type(4))) float floatx4;

__device__ __forceinline__ short bf16_of(float f) {
  __hip_bfloat16 h = __float2bfloat16(f);
  return __builtin_bit_cast(short, h);
}

__device__ __forceinline__ short8_t cvt8(float4 x, float4 y) {
  short8_t v;
  v[0] = bf16_of(x.x); v[1] = bf16_of(x.y); v[2] = bf16_of(x.z); v[3] = bf16_of(x.w);
  v[4] = bf16_of(y.x); v[5] = bf16_of(y.y); v[6] = bf16_of(y.z); v[7] = bf16_of(y.w);
  return v;
}

// ---------- async global->LDS helper (16B per lane)
__device__ __forceinline__ void gload_lds16(void* l, const void* g) {
#if defined(__has_builtin) && __has_builtin(__builtin_amdgcn_global_load_lds)
  __builtin_amdgcn_global_load_lds((const __attribute__((address_space(1))) void*)g,
                                   (__attribute__((address_space(3))) void*)l, 16, 0, 0);
#else
  *(float4*)l = *(const float4*)g;
#endif
}

// ---------- Kernel 1: fkT[oc][pd] = sum_k fb[p,o,k] * Wf[d*32+c, k] / 1024
__global__ __launch_bounds__(256) void fk_kernel(const float* __restrict__ fb,
                                                 const float* __restrict__ Wf,
                                                 float* __restrict__ fkT) {
  int gid = blockIdx.x * 256 + threadIdx.x;
#pragma unroll
  for (int i = 0; i < 4; ++i) {
    int idx = gid + i * 65536;
    int pd = idx & 511;
    int oc = idx >> 9;
    int o = oc >> 5, c = oc & 31;
    int p = pd >> 5, d = pd & 31;
    const float4* fb4 = (const float4*)(fb + (p * 16 + o) * 16);
    const float4* wf4 = (const float4*)(Wf + (d * 32 + c) * 16);
    float s = 0.f;
#pragma unroll
    for (int q = 0; q < 4; ++q) {
      float4 a = fb4[q], w = wf4[q];
      s += a.x * w.x + a.y * w.y + a.z * w.z + a.w * w.w;
    }
    fkT[idx] = s * (1.0f / 1024.0f);
  }
}

// ---------- Kernel 2: contiguous-stream MFMA. Block = (b, mt, ks): 16 rows, 32 n-lines.
// Stage [2n x 16m x 1KB] into LDS via global_load_lds, one full contiguous 1KB line per
// wave-instruction (source pre-XOR'd at 16B granule: (lane*16)^((m&7)<<4); ds_read uses
// the same XOR -> spread banks). 8 waves x 2 o x 2 c-halves = 4 MFMAs/buffer/wave.
__global__ __launch_bounds__(512, 4) void gemm_stream(const float* __restrict__ kb,
                                                      const float* __restrict__ x,
                                                      const float* __restrict__ Wk,
                                                      float* __restrict__ x1p) {
  __shared__ __align__(16) char lds[2][32 * 1024];   // 2 x 32KB
  const int tid = threadIdx.x;
  const int bid = blockIdx.x;            // 512 = ((b*16+mt)*8)+ks
  const int ks = bid & 7;
  const int mt = (bid >> 3) & 15;
  const int b  = bid >> 7;
  const int wave = tid >> 6, lane = tid & 63;
  const int r = lane & 15, g = lane >> 4;

  // staging assignment: wave w, round i -> line idx = i*8+w: n_l = idx>>4, m_l = idx&15
  const float* srcbase[4];
  int ldsoff[4];
#pragma unroll
  for (int i = 0; i < 4; ++i) {
    int idx = i * 8 + wave;
    int n_l = idx >> 4, m_l = idx & 15;
    srcbase[i] = kb + (size_t)(b * 256 + mt * 16 + m_l) * 65536
                 + (size_t)(ks * 32 + n_l) * 256
                 + (((lane * 16) ^ ((m_l & 7) << 4)) >> 2);
    ldsoff[i] = (n_l * 16 + m_l) * 1024 + lane * 16;
  }

  // Wk rows r (c-half 0) and r+16 (c-half 1), k-slice (g&1)*8
  float w0[8], w1[8];
  {
    const float4* p0 = (const float4*)(Wk + r * 16 + (g & 1) * 8);
    const float4* p1 = (const float4*)(Wk + (r + 16) * 16 + (g & 1) * 8);
    float4 a = p0[0], bq = p0[1], cq = p1[0], dq = p1[1];
    w0[0] = a.x; w0[1] = a.y; w0[2] = a.z; w0[3] = a.w;
    w0[4] = bq.x; w0[5] = bq.y; w0[6] = bq.z; w0[7] = bq.w;
    w1[0] = cq.x; w1[1] = cq.y; w1[2] = cq.z; w1[3] = cq.w;
    w1[4] = dq.x; w1[5] = dq.y; w1[6] = dq.z; w1[7] = dq.w;
  }

  const int o0 = wave, o1 = wave + 8;
  floatx4 acc00 = {0.f, 0.f, 0.f, 0.f}, acc01 = {0.f, 0.f, 0.f, 0.f};
  floatx4 acc10 = {0.f, 0.f, 0.f, 0.f}, acc11 = {0.f, 0.f, 0.f, 0.f};

  // A ds_read addressing (chunk-invariant): row (g>>1 picks staged n-line, r picks m)
  const int arow = ((g >> 1) * 16 + r) * 1024;
  const int sw = (r & 7) << 4;
  const int aoff0 = o0 * 64 + (g & 1) * 32;
  const int aoff1 = o1 * 64 + (g & 1) * 32;
  // x: [b, n, o, c]; per lane n = nbase + (g>>1), c = ch*16 + r
  const float* gx = x + (size_t)(b * 256 + ks * 32 + (g >> 1)) * 512 + r;

#define STAGE(buf_, t_)                                                      \
  {                                                                          \
    _Pragma("unroll") for (int i = 0; i < 4; ++i)                            \
        gload_lds16(lds[buf_] + ldsoff[i], srcbase[i] + (size_t)(t_)*512);   \
  }
#define COMPUTE(buf_, t_)                                                    \
  {                                                                          \
    const float* px = gx + (size_t)(t_)*1024;                                \
    float xv00 = px[o0 * 32], xv01 = px[o0 * 32 + 16];                       \
    float xv10 = px[o1 * 32], xv11 = px[o1 * 32 + 16];                       \
    const char* base = lds[buf_] + arow;                                     \
    float4 a0x = *(const float4*)(base + (aoff0 ^ sw));                      \
    float4 a0y = *(const float4*)(base + ((aoff0 + 16) ^ sw));               \
    float4 a1x = *(const float4*)(base + (aoff1 ^ sw));                      \
    float4 a1y = *(const float4*)(base + ((aoff1 + 16) ^ sw));               \
    short8_t af0 = cvt8(a0x, a0y);                                           \
    short8_t af1 = cvt8(a1x, a1y);                                           \
    short8_t b00, b01, b10, b11;                                             \
    _Pragma("unroll") for (int j = 0; j < 8; ++j) {                          \
      b00[j] = bf16_of(xv00 * w0[j]);                                        \
      b01[j] = bf16_of(xv01 * w1[j]);                                        \
      b10[j] = bf16_of(xv10 * w0[j]);                                        \
      b11[j] = bf16_of(xv11 * w1[j]);                                        \
    }                                                                        \
    acc00 = __builtin_amdgcn_mfma_f32_16x16x32_bf16(af0, b00, acc00, 0, 0, 0); \
    acc01 = __builtin_amdgcn_mfma_f32_16x16x32_bf16(af0, b01, acc01, 0, 0, 0); \
    acc10 = __builtin_amdgcn_mfma_f32_16x16x32_bf16(af1, b10, acc10, 0, 0, 0); \
    acc11 = __builtin_amdgcn_mfma_f32_16x16x32_bf16(af1, b11, acc11, 0, 0, 0); \
  }

  STAGE(0, 0);
  __syncthreads();
  for (int t = 0; t < 16; ++t) {
    int cur = t & 1;
    if (t < 15) STAGE(cur ^ 1, t + 1);   // issue next buffer before compute
    COMPUTE(cur, t);
    __syncthreads();                     // drains stage(t+1), protects buf reuse
  }
#undef STAGE
#undef COMPUTE

  // C/D: col = lane&15 (c within half), row = g*4 + j (m within tile)
  float* op = x1p + (size_t)ks * 524288 + (size_t)(b * 256 + mt * 16 + g * 4) * 512 + r;
#pragma unroll
  for (int j = 0; j < 4; ++j) {
    float* rowp = op + (size_t)j * 512;
    rowp[o0 * 32]      = acc00[j];
    rowp[o0 * 32 + 16] = acc01[j];
    rowp[o1 * 32]      = acc10[j];
    rowp[o1 * 32 + 16] = acc11[j];
  }
}

// ---------- Kernel 3: x1 = sum of 8 partial slices
__global__ __launch_bounds__(256) void reduce8(const float* __restrict__ x1p,
                                               float* __restrict__ x1) {
  int i = blockIdx.x * 256 + threadIdx.x;    // 131072 float4s
  float4 s = ((const float4*)x1p)[i];
#pragma unroll
  for (int sl = 1; sl < 8; ++sl) {
    float4 a = ((const float4*)(x1p + (size_t)sl * 524288))[i];
    s.x += a.x; s.y += a.y; s.z += a.z; s.w += a.w;
  }
  ((float4*)x1)[i] = s;
}

// ---------- Kernel 4: out[bm, pd] = sum_oc x1[bm,oc] * fkT[oc,pd] + bias[pd&31]
__global__ __launch_bounds__(256) void fiber_kernel(const float* __restrict__ x1,
                                                    const float* __restrict__ fkT,
                                                    const float* __restrict__ bias,
                                                    float* __restrict__ out) {
  __shared__ float At[32][68];
  __shared__ float Bt[32][64];
  const int tid = threadIdx.x;
  const int bx = blockIdx.x & 7;
  const int by = blockIdx.x >> 3;
  const int tr = tid >> 4, tc = tid & 15;
  const int row0 = by * 64, col0 = bx * 64;
  float acc[4][4] = {};
  for (int kc = 0; kc < 512; kc += 32) {
    __syncthreads();
    {
      int r8 = tid >> 3, kq = tid & 7;
#pragma unroll
      for (int ii = 0; ii < 2; ++ii) {
        int rr = r8 + ii * 32;
        float4 a = *(const float4*)(x1 + (size_t)(row0 + rr) * 512 + kc + kq * 4);
        At[kq * 4 + 0][rr] = a.x; At[kq * 4 + 1][rr] = a.y;
        At[kq * 4 + 2][rr] = a.z; At[kq * 4 + 3][rr] = a.w;
      }
#pragma unroll
      for (int ii = 0; ii < 2; ++ii) {
        int idx = tid + ii * 256;
        int k = idx >> 4, c4 = idx & 15;
        *(float4*)&Bt[k][c4 * 4] = *(const float4*)(fkT + (kc + k) * 512 + col0 + c4 * 4);
      }
    }
    __syncthreads();
#pragma unroll 8
    for (int k = 0; k < 32; ++k) {
      float4 av = *(const float4*)&At[k][tr * 4];
      float4 bv = *(const float4*)&Bt[k][tc * 4];
      float ar[4] = {av.x, av.y, av.z, av.w};
      float br[4] = {bv.x, bv.y, bv.z, bv.w};
#pragma unroll
      for (int i = 0; i < 4; ++i)
#pragma unroll
        for (int j = 0; j < 4; ++j)
          acc[i][j] = fmaf(ar[i], br[j], acc[i][j]);
    }
  }
  float4 bias4 = *(const float4*)(bias + ((tc * 4) & 31));
  float bb[4] = {bias4.x, bias4.y, bias4.z, bias4.w};
#pragma unroll
  for (int i = 0; i < 4; ++i) {
    float4 o4;
    o4.x = acc[i][0] + bb[0]; o4.y = acc[i][1] + bb[1];
    o4.z = acc[i][2] + bb[2]; o4.w = acc[i][3] + bb[3];
    *(float4*)(out + (size_t)(row0 + tr * 4 + i) * 512 + col0 + tc * 4) = o4;
  }
}

// ---------- fallback: single-pass direct (only if ws too small)
__global__ __launch_bounds__(256) void gemm_direct(const float* __restrict__ kb,
                                                   const float* __restrict__ x,
                                                   const float* __restrict__ Wk,
                                                   float* __restrict__ x1) {
  const int tid = threadIdx.x;
  const int bid = blockIdx.x;
  const int bo = bid & 63;
  const int b = bo >> 4, o = bo & 15;
  const int wave = tid >> 6, lane = tid & 63;
  const int mt = (bid >> 6) * 4 + wave;
  const int r = lane & 15, g = lane >> 4;
  const float* gA = kb + (size_t)(b * 256 + mt * 16 + r) * 65536
                    + (g >> 1) * 256 + o * 16 + (g & 1) * 8;
  const float* gx = x + ((size_t)(b * 256) * 16 + o) * 32 + (g >> 1) * 512 + r;
  float w0[8], w1[8];
  {
    const float4* p0 = (const float4*)(Wk + r * 16 + (g & 1) * 8);
    const float4* p1 = (const float4*)(Wk + (r + 16) * 16 + (g & 1) * 8);
    float4 a = p0[0], bq = p0[1], cq = p1[0], dq = p1[1];
    w0[0] = a.x; w0[1] = a.y; w0[2] = a.z; w0[3] = a.w;
    w0[4] = bq.x; w0[5] = bq.y; w0[6] = bq.z; w0[7] = bq.w;
    w1[0] = cq.x; w1[1] = cq.y; w1[2] = cq.z; w1[3] = cq.w;
    w1[4] = dq.x; w1[5] = dq.y; w1[6] = dq.z; w1[7] = dq.w;
  }
  floatx4 acc0 = {0.f, 0.f, 0.f, 0.f}, acc1 = {0.f, 0.f, 0.f, 0.f};
  float4 aAx, aAy, aBx, aBy;
  float xA0, xA1, xB0, xB1;
#define LOADF(sx, sy, v0, v1, kk_)                       \
  {                                                      \
    const float* pa = gA + (size_t)(kk_) * 16;           \
    sx = *(const float4*)pa;                             \
    sy = *(const float4*)(pa + 4);                       \
    const float* px = gx + (size_t)(kk_) * 32;           \
    v0 = px[0];                                          \
    v1 = px[16];                                         \
  }
#define COMPUTE(sx, sy, v0, v1)                          \
  {                                                      \
    short8_t afr = cvt8(sx, sy);                         \
    short8_t bf0, bf1;                                   \
    _Pragma("unroll") for (int j = 0; j < 8; ++j) {      \
      bf0[j] = bf16_of(v0 * w0[j]);                      \
      bf1[j] = bf16_of(v1 * w1[j]);                      \
    }                                                    \
    acc0 = __builtin_amdgcn_mfma_f32_16x16x32_bf16(afr, bf0, acc0, 0, 0, 0); \
    acc1 = __builtin_amdgcn_mfma_f32_16x16x32_bf16(afr, bf1, acc1, 0, 0, 0); \
  }
  LOADF(aAx, aAy, xA0, xA1, 0);
  for (int kk = 0; kk < 4096; kk += 64) {
    LOADF(aBx, aBy, xB0, xB1, kk + 32);
    COMPUTE(aAx, aAy, xA0, xA1);
    if (kk + 64 < 4096) LOADF(aAx, aAy, xA0, xA1, kk + 64);
    COMPUTE(aBx, aBy, xB0, xB1);
  }
#undef LOADF
#undef COMPUTE
  float* op = x1 + (size_t)(b * 256 + mt * 16 + g * 4) * 512 + o * 32 + r;
#pragma unroll
  for (int j = 0; j < 4; ++j) {
    op[(size_t)j * 512] = acc0[j];
    op[(size_t)j * 512 + 16] = acc1[j];
  }
}

extern "C" void kernel_launch(void* const* d_in, const int* in_sizes, int n_in,
                              void* d_out, int out_size, void* d_ws, size_t ws_size,
                              hipStream_t stream) {
  const float* x    = (const float*)d_in[0];  // [4,256,16,32]
  const float* kbas = (const float*)d_in[1];  // [4,256,256,16,16]
  const float* fb   = (const float*)d_in[2];  // [16,16,16]
  const float* Wk   = (const float*)d_in[3];  // [32,16]
  const float* Wf   = (const float*)d_in[4];  // [1024,16]
  const float* bias = (const float*)d_in[5];  // [32]
  float* out = (float*)d_out;                 // [4,256,16,32] f32

  float* fkT = (float*)d_ws;          // 1 MB
  float* x1  = fkT + 262144;          // 2 MB
  float* x1p = x1 + 524288;           // 8 x 2 MB partial slices
  const size_t need = (262144 + 524288 + 8 * 524288) * sizeof(float);

  fk_kernel<<<256, 256, 0, stream>>>(fb, Wf, fkT);
  if (ws_size >= need) {
    gemm_stream<<<512, 512, 0, stream>>>(kbas, x, Wk, x1p);
    reduce8<<<512, 256, 0, stream>>>(x1p, x1);
  } else {
    gemm_direct<<<256, 256, 0, stream>>>(kbas, x, Wk, x1);
  }
  fiber_kernel<<<128, 256, 0, stream>>>(x1, fkT, bias, out);
}